// Round 4
// baseline (273.855 us; speedup 1.0000x reference)
//
#include <hip/hip_runtime.h>
#include <math.h>

// Problem constants
#define NB 4      // batch
#define C  128    // channels (q/k/v/out)
#define CCH 256   // context channels
#define HH 64
#define WW 64
#define NN 4096   // HH*WW
#define HC 32
#define WC 32
#define PP 66     // padded spatial dim for conv input (64 + 2 halo)
#define KSPLIT 8  // flash split-K factor

typedef unsigned short u16;
typedef unsigned int uint32;
typedef short s16x8 __attribute__((ext_vector_type(8)));    // 8 bf16 = 4 VGPRs (MFMA A/B frag)
typedef float f32x4 __attribute__((ext_vector_type(4)));    // 16x16 MFMA C/D frag
typedef float f32x16 __attribute__((ext_vector_type(16)));  // 32x32 MFMA C/D frag

// fp32 -> bf16 round-to-nearest-even
__device__ __forceinline__ u16 f2bf(float f) {
    uint32 u = __float_as_uint(f);
    u += 0x7fffu + ((u >> 16) & 1u);
    return (u16)(u >> 16);
}

// ---------------------------------------------------------------------------
// 1) Bilinear 2x upsample, half-pixel centers, clamped edges.
// ---------------------------------------------------------------------------
__global__ __launch_bounds__(256) void upsample_kernel(const float* __restrict__ ctx,
                                                       float* __restrict__ out) {
    int idx = blockIdx.x * 256 + threadIdx.x;          // over NB*CCH*NN
    int x = idx & 63, y = (idx >> 6) & 63, bc = idx >> 12;
    float sy = y * 0.5f - 0.25f;
    float sx = x * 0.5f - 0.25f;
    int y0 = (int)floorf(sy), x0 = (int)floorf(sx);
    float wy = sy - (float)y0, wx = sx - (float)x0;
    int y0c = y0 < 0 ? 0 : y0;
    int y1c = (y0 + 1 > HC - 1) ? HC - 1 : y0 + 1;
    int x0c = x0 < 0 ? 0 : x0;
    int x1c = (x0 + 1 > WC - 1) ? WC - 1 : x0 + 1;
    const float* p = ctx + (size_t)bc * (HC * WC);
    float v00 = p[y0c * WC + x0c], v01 = p[y0c * WC + x1c];
    float v10 = p[y1c * WC + x0c], v11 = p[y1c * WC + x1c];
    out[idx] = (1.f - wy) * ((1.f - wx) * v00 + wx * v01)
             +        wy  * ((1.f - wx) * v10 + wx * v11);
}

// ---------------------------------------------------------------------------
// 1b) Zero the padded att_t buffer (border must be 0; ws is poisoned each call)
// ---------------------------------------------------------------------------
__global__ __launch_bounds__(256) void zero_att(uint4* __restrict__ att_t) {
    int idx = blockIdx.x * 256 + threadIdx.x;  // 1089*256 = NB*66*66*128*2/16
    att_t[idx] = make_uint4(0, 0, 0, 0);
}

// ---------------------------------------------------------------------------
// 1c) Zero the flash accumulator (acc 2,097,152 f32 + lacc 16,384 f32)
// ---------------------------------------------------------------------------
__global__ __launch_bounds__(256) void zero_acc(uint4* __restrict__ p) {
    int idx = blockIdx.x * 256 + threadIdx.x;  // 2064*256 = 2,113,536 f32 /4
    p[idx] = make_uint4(0, 0, 0, 0);
}

// ---------------------------------------------------------------------------
// 1d) Weight prep: Wp fp32 [co][ci][ky][kx] -> wt bf16 [pos][cib][co][ci32]
// ---------------------------------------------------------------------------
__global__ __launch_bounds__(256) void wprep(const float* __restrict__ Wp,
                                             u16* __restrict__ wt) {
    int idx = blockIdx.x * 256 + threadIdx.x;   // 9*4*128*32 = 147456
    int ciin = idx & 31;
    int co = (idx >> 5) & 127;
    int cb = (idx >> 12) & 3;
    int pos = idx >> 14;            // 0..8
    int ky = pos / 3, kx = pos - ky * 3;
    int ci = cb * 32 + ciin;
    wt[idx] = f2bf(Wp[((size_t)(co * C + ci) * 3 + ky) * 3 + kx]);
}

// ---------------------------------------------------------------------------
// 2a) Projection GEMM, bf16 TRANSPOSED output: outT[b][n][co]  (for Q, K)
// ---------------------------------------------------------------------------
__global__ __launch_bounds__(256) void proj_gemm_tn(const float* __restrict__ in,
                                                    const float* __restrict__ W,
                                                    const float* __restrict__ bias,
                                                    u16* __restrict__ outT, int Cin) {
    __shared__ float ws[16 * 68];
    __shared__ float xs[16 * 68];
    int b = blockIdx.z;
    int co0 = blockIdx.y * 64;
    int n0 = blockIdx.x * 64;
    int tid = threadIdx.x;
    int tx = tid & 15, ty = tid >> 4;
    float acc[4][4] = {};
    const float* inb = in + (size_t)b * Cin * NN + n0;
    for (int c0 = 0; c0 < Cin; c0 += 16) {
        __syncthreads();
        {
            int co = tid >> 2;
            int ck4 = (tid & 3) * 4;
            float4 wv = *(const float4*)(W + (size_t)(co0 + co) * Cin + c0 + ck4);
            ws[(ck4 + 0) * 68 + co] = wv.x;
            ws[(ck4 + 1) * 68 + co] = wv.y;
            ws[(ck4 + 2) * 68 + co] = wv.z;
            ws[(ck4 + 3) * 68 + co] = wv.w;
        }
        {
            int nn = (tid & 15) * 4;
            int cik = tid >> 4;
            float4 v = *(const float4*)(inb + (size_t)(c0 + cik) * NN + nn);
            *(float4*)&xs[cik * 68 + nn] = v;
        }
        __syncthreads();
#pragma unroll
        for (int cik = 0; cik < 16; cik++) {
            float4 wv = *(const float4*)&ws[cik * 68 + ty * 4];
            float4 xv = *(const float4*)&xs[cik * 68 + tx * 4];
            float wa[4] = {wv.x, wv.y, wv.z, wv.w};
            float xa[4] = {xv.x, xv.y, xv.z, xv.w};
#pragma unroll
            for (int i = 0; i < 4; i++)
#pragma unroll
                for (int j = 0; j < 4; j++) acc[i][j] += wa[i] * xa[j];
        }
    }
    float bvv[4];
#pragma unroll
    for (int i = 0; i < 4; i++) bvv[i] = bias[co0 + ty * 4 + i];
#pragma unroll
    for (int j = 0; j < 4; j++) {
        ushort4 o = make_ushort4(f2bf(acc[0][j] + bvv[0]), f2bf(acc[1][j] + bvv[1]),
                                 f2bf(acc[2][j] + bvv[2]), f2bf(acc[3][j] + bvv[3]));
        *(ushort4*)(outT + (size_t)b * NN * C + (size_t)(n0 + tx * 4 + j) * C + co0 + ty * 4) = o;
    }
}

// ---------------------------------------------------------------------------
// 2b) Projection GEMM, bf16 NORMAL output: outN[b][co][n]  (for V)
// ---------------------------------------------------------------------------
__global__ __launch_bounds__(256) void proj_gemm_nn(const float* __restrict__ in,
                                                    const float* __restrict__ W,
                                                    const float* __restrict__ bias,
                                                    u16* __restrict__ outN, int Cin) {
    __shared__ float ws[16 * 68];
    __shared__ float xs[16 * 68];
    int b = blockIdx.z;
    int co0 = blockIdx.y * 64;
    int n0 = blockIdx.x * 64;
    int tid = threadIdx.x;
    int tx = tid & 15, ty = tid >> 4;
    float acc[4][4] = {};
    const float* inb = in + (size_t)b * Cin * NN + n0;
    for (int c0 = 0; c0 < Cin; c0 += 16) {
        __syncthreads();
        {
            int co = tid >> 2;
            int ck4 = (tid & 3) * 4;
            float4 wv = *(const float4*)(W + (size_t)(co0 + co) * Cin + c0 + ck4);
            ws[(ck4 + 0) * 68 + co] = wv.x;
            ws[(ck4 + 1) * 68 + co] = wv.y;
            ws[(ck4 + 2) * 68 + co] = wv.z;
            ws[(ck4 + 3) * 68 + co] = wv.w;
        }
        {
            int nn = (tid & 15) * 4;
            int cik = tid >> 4;
            float4 v = *(const float4*)(inb + (size_t)(c0 + cik) * NN + nn);
            *(float4*)&xs[cik * 68 + nn] = v;
        }
        __syncthreads();
#pragma unroll
        for (int cik = 0; cik < 16; cik++) {
            float4 wv = *(const float4*)&ws[cik * 68 + ty * 4];
            float4 xv = *(const float4*)&xs[cik * 68 + tx * 4];
            float wa[4] = {wv.x, wv.y, wv.z, wv.w};
            float xa[4] = {xv.x, xv.y, xv.z, xv.w};
#pragma unroll
            for (int i = 0; i < 4; i++)
#pragma unroll
                for (int j = 0; j < 4; j++) acc[i][j] += wa[i] * xa[j];
        }
    }
#pragma unroll
    for (int i = 0; i < 4; i++) {
        int co = co0 + ty * 4 + i;
        float bv = bias[co];
        ushort4 o = make_ushort4(f2bf(acc[i][0] + bv), f2bf(acc[i][1] + bv),
                                 f2bf(acc[i][2] + bv), f2bf(acc[i][3] + bv));
        *(ushort4*)(outN + (size_t)b * C * NN + (size_t)co * NN + n0 + tx * 4) = o;
    }
}

// ---------------------------------------------------------------------------
// 3) Flash attention, 32x32x16 MFMA, Q in registers, split-K x8 with fp32
//    atomic accumulation (no running max; partials combine by addition).
//    Block: 4 waves = 128 queries; each block covers 512 keys (8 iters of 64).
//    Grid 1024 = 4 b x 32 qtiles x 8 splits. LDS 51.2 KB -> 3 blocks/CU.
//    acc layout [b][n][c] fp32; lacc [b][n] fp32.
// ---------------------------------------------------------------------------
__global__ __launch_bounds__(256) void flash_mfma(const u16* __restrict__ qt_p,
                                                  const u16* __restrict__ kt_p,
                                                  const u16* __restrict__ vt_p,
                                                  float* __restrict__ acc,
                                                  float* __restrict__ lacc) {
    __shared__ u16 ks[64 * 128];     // [key][ch]   chunk-XOR16 swizzled, 16 KB
    __shared__ u16 vs[128 * 64];     // [ch][key]   chunk-XOR8 swizzled,  16 KB
    __shared__ u16 ps[4 * 32 * 72];  // per-wave P [q32][key64] pad 72, 18 KB

    int ib = blockIdx.x;
    int b = (ib & 7) >> 1;                       // batch -> XCD pair (L2 locality)
    int rest = ((ib >> 3) << 1) | (ib & 1);      // 0..255
    int qtile = rest >> 3;                       // 0..31
    int split = rest & 7;                        // 0..7
    int n0 = qtile * 128;
    int tid = threadIdx.x;
    int w = tid >> 6;            // wave 0..3
    int lane = tid & 63;
    int l31 = lane & 31;
    int half = lane >> 5;        // 0/1

    const u16* qtb = qt_p + (size_t)b * NN * C;
    const u16* ktb = kt_p + (size_t)b * NN * C;
    const u16* vtb = vt_p + (size_t)b * C * NN;

    auto stageK = [&](int m0) {
#pragma unroll
        for (int t = 0; t < 4; t++) {
            int CI = (w * 4 + t) * 64 + lane;                 // chunk index 0..1023
            int r = CI >> 4;                                  // key row (0..63)
            int lc = (CI & 15) ^ (r & 15);                    // logical chunk
            __builtin_amdgcn_global_load_lds(
                (const __attribute__((address_space(1))) void*)(ktb + (size_t)(m0 + r) * C + lc * 8),
                (__attribute__((address_space(3))) void*)&ks[(w * 4 + t) * 512], 16, 0, 0);
        }
    };
    auto stageV = [&](int m0) {
#pragma unroll
        for (int t = 0; t < 4; t++) {
            int CI = (w * 4 + t) * 64 + lane;
            int c = CI >> 3;                                  // channel row (0..127)
            int lc = (CI & 7) ^ (c & 7);
            __builtin_amdgcn_global_load_lds(
                (const __attribute__((address_space(1))) void*)(vtb + (size_t)c * NN + m0 + lc * 8),
                (__attribute__((address_space(3))) void*)&vs[(w * 4 + t) * 512], 16, 0, 0);
        }
    };

    // ---- Q A-fragments into registers (once): 8 k-groups of 16 ch ----
    int qrow = n0 + w * 32 + l31;
    s16x8 qfrag[8];
#pragma unroll
    for (int kg = 0; kg < 8; kg++)
        qfrag[kg] = *(const s16x8*)(qtb + (size_t)qrow * C + kg * 16 + half * 8);

    int m_base = split * 512;
    stageK(m_base);
    __syncthreads();

    f32x16 oacc[4];
#pragma unroll
    for (int ct = 0; ct < 4; ct++)
#pragma unroll
        for (int i = 0; i < 16; i++) oacc[ct][i] = 0.f;
    float lsum[16];
#pragma unroll
    for (int r = 0; r < 16; r++) lsum[r] = 0.f;

    int row_base = half * 4;

    for (int it = 0; it < 512 / 64; it++) {
        int m0 = m_base + it * 64;
        stageV(m0);                               // async, drains at barrier 1

        // ---- S = Q·K^T : 32q x 64k (2 n-tiles), K-dim = 128 ch ----
        f32x16 sacc[2];
#pragma unroll
        for (int nt = 0; nt < 2; nt++)
#pragma unroll
            for (int i = 0; i < 16; i++) sacc[nt][i] = 0.f;
#pragma unroll
        for (int kg = 0; kg < 8; kg++) {
            int pc = (kg * 2 + half) ^ (lane & 15);           // ks physical chunk
#pragma unroll
            for (int nt = 0; nt < 2; nt++) {
                s16x8 kf = *(const s16x8*)&ks[(nt * 32 + l31) * 128 + pc * 8];
                sacc[nt] = __builtin_amdgcn_mfma_f32_32x32x16_bf16(qfrag[kg], kf, sacc[nt], 0, 0, 0);
            }
        }
        __syncthreads();                          // V staged; all waves done with ks
        if (it < 7) stageK(m0 + 64);              // async, drains at barrier 2

        // ---- P = exp(S); accumulate l; write P [q][key] bf16 ----
#pragma unroll
        for (int nt = 0; nt < 2; nt++)
#pragma unroll
            for (int r = 0; r < 16; r++) {
                float p = __expf(sacc[nt][r]);
                lsum[r] += p;
                int row = (r & 3) + 8 * (r >> 2) + row_base;
                ps[w * 2304 + row * 72 + nt * 32 + l31] = f2bf(p);
            }

        // ---- O += P·V : 32q x 128ch (4 n-tiles), K-dim = 64 keys ----
#pragma unroll
        for (int kg = 0; kg < 4; kg++) {
            s16x8 pf = *(const s16x8*)&ps[w * 2304 + l31 * 72 + kg * 16 + half * 8];
            int pc = (kg * 2 + half) ^ (lane & 7);            // vs physical chunk
#pragma unroll
            for (int ct = 0; ct < 4; ct++) {
                s16x8 vf = *(const s16x8*)&vs[(ct * 32 + l31) * 64 + pc * 8];
                oacc[ct] = __builtin_amdgcn_mfma_f32_32x32x16_bf16(pf, vf, oacc[ct], 0, 0, 0);
            }
        }
        __syncthreads();                          // K(it+1) staged; all done with vs
    }

    // ---- epilogue: reduce l across 32 key-lanes; atomically add partials ----
#pragma unroll
    for (int r = 0; r < 16; r++) {
        float s = lsum[r];
#pragma unroll
        for (int off = 1; off < 32; off <<= 1) s += __shfl_xor(s, off);
        lsum[r] = s;   // offsets 1..16 stay within each 32-lane half
    }
    float* accb = acc + (size_t)b * NN * C;
    float* lb = lacc + (size_t)b * NN;
#pragma unroll
    for (int r = 0; r < 16; r++) {
        int q = n0 + w * 32 + (r & 3) + 8 * (r >> 2) + row_base;
#pragma unroll
        for (int ct = 0; ct < 4; ct++)
            atomicAdd(&accb[(size_t)q * C + ct * 32 + l31], oacc[ct][r]);
        if (l31 == 0) atomicAdd(&lb[q], lsum[r]);
    }
}

// ---------------------------------------------------------------------------
// 3b) Combine: att_t[b][y+1][x+1][c] = bf16( acc[b][n][c] / lacc[b][n] )
// ---------------------------------------------------------------------------
__global__ __launch_bounds__(256) void flash_combine(const float* __restrict__ acc,
                                                     const float* __restrict__ lacc,
                                                     u16* __restrict__ att_t) {
    int idx = blockIdx.x * 256 + threadIdx.x;    // over NB*NN*C = 2,097,152
    int c = idx & 127;
    int n = (idx >> 7) & 4095;
    int b = idx >> 19;
    float val = acc[idx] / lacc[b * NN + n];
    int y = n >> 6, x = n & 63;
    att_t[((size_t)b * PP * PP + (size_t)(y + 1) * PP + (x + 1)) * C + c] = f2bf(val);
}

// ---------------------------------------------------------------------------
// 4) Implicit-GEMM MFMA conv3x3 + residual.
// ---------------------------------------------------------------------------
__global__ __launch_bounds__(256) void conv3x3_mfma(const u16* __restrict__ att_t,
                                                    const u16* __restrict__ wt,
                                                    const float* __restrict__ bp,
                                                    const float* __restrict__ sr,
                                                    const float* __restrict__ gamma,
                                                    float* __restrict__ out) {
    __shared__ u16 in_s[2][4 * 204 * 8];   // per buf: 4 planes x (3*68=204) chunks x 16B
    int ib = blockIdx.x;
    int b = (ib & 7) >> 1;                 // batch -> XCD pair
    int y = ((ib >> 3) << 1) | (ib & 1);   // output row 0..63
    int tid = threadIdx.x;
    int w = tid >> 6, lane = tid & 63, l = tid & 15, quad = (tid >> 4) & 3;
    const u16* ab = att_t + (size_t)b * (PP * PP * C);

    auto stage = [&](int cib, int bufi) {
        u16* base = &in_s[bufi][w * 204 * 8];
        const u16* gsrc = ab + cib * 32 + w * 8;
#pragma unroll
        for (int t = 0; t < 4; t++) {
            int rem = t * 64 + lane;          // valid < 204
            int r = rem / 68, xp = rem - r * 68;
            if (t < 3 || lane < 12)
                __builtin_amdgcn_global_load_lds(
                    (const __attribute__((address_space(1))) void*)(gsrc + (size_t)((y + r) * PP + xp) * C),
                    (__attribute__((address_space(3))) void*)(base + (size_t)t * 64 * 8), 16, 0, 0);
        }
    };

    f32x4 acc[2][4];
#pragma unroll
    for (int cf = 0; cf < 2; cf++)
#pragma unroll
        for (int nf = 0; nf < 4; nf++) acc[cf][nf] = (f32x4){0.f, 0.f, 0.f, 0.f};
    int cow = w * 32;

    stage(0, 0);
    __syncthreads();
#pragma unroll
    for (int cib = 0; cib < 4; cib++) {
        if (cib < 3) stage(cib + 1, (cib + 1) & 1);
        const u16* bufc = &in_s[cib & 1][0];
#pragma unroll
        for (int ky = 0; ky < 3; ky++)
#pragma unroll
            for (int kx = 0; kx < 3; kx++) {
                int pos = ky * 3 + kx;
                s16x8 wf[2];
#pragma unroll
                for (int cf = 0; cf < 2; cf++)
                    wf[cf] = *(const s16x8*)&wt[((size_t)(pos * 4 + cib) * C + cow + cf * 16 + l) * 32 + quad * 8];
#pragma unroll
                for (int nf = 0; nf < 4; nf++) {
                    s16x8 inf = *(const s16x8*)&bufc[(quad * 204 + ky * 68 + nf * 16 + l + kx) * 8];
                    acc[0][nf] = __builtin_amdgcn_mfma_f32_16x16x32_bf16(wf[0], inf, acc[0][nf], 0, 0, 0);
                    acc[1][nf] = __builtin_amdgcn_mfma_f32_16x16x32_bf16(wf[1], inf, acc[1][nf], 0, 0, 0);
                }
            }
        __syncthreads();
    }

    float g = gamma[0];
    float* ob = out + (size_t)b * C * NN;
    const float* sb = sr + (size_t)b * C * NN;
#pragma unroll
    for (int cf = 0; cf < 2; cf++)
#pragma unroll
        for (int r = 0; r < 4; r++) {
            int co = cow + cf * 16 + quad * 4 + r;
            float bias = bp[co];
#pragma unroll
            for (int nf = 0; nf < 4; nf++) {
                size_t oo = (size_t)co * NN + y * 64 + nf * 16 + l;
                ob[oo] = sb[oo] + g * (acc[cf][nf][r] + bias);
            }
        }
}

// ---------------------------------------------------------------------------
extern "C" void kernel_launch(void* const* d_in, const int* in_sizes, int n_in,
                              void* d_out, int out_size, void* d_ws, size_t ws_size,
                              hipStream_t stream) {
    const float* sr    = (const float*)d_in[0];
    const float* ctx   = (const float*)d_in[1];
    const float* Wq    = (const float*)d_in[2];
    const float* bq    = (const float*)d_in[3];
    const float* Wk    = (const float*)d_in[4];
    const float* bk    = (const float*)d_in[5];
    const float* Wv    = (const float*)d_in[6];
    const float* bv    = (const float*)d_in[7];
    const float* Wp    = (const float*)d_in[8];
    const float* bp    = (const float*)d_in[9];
    const float* gamma = (const float*)d_in[10];
    float* out = (float*)d_out;

    // ws layout (bytes), 33.6 MB total:
    //   att_t bf16 padded [B][66][66][C] : @0,      4,460,544 B
    //   ctx_up fp32 [B][CCH][N]          : @5 MB,   16 MB
    //     (acc fp32 [B][N][C] 8,388,608 B + lacc [B][N] 65,536 B overlay this
    //      region once ctx_up is dead after the V projection)
    //   q_t bf16 [B][N][C]               : @21 MB,  4 MB
    //   k_t bf16 [B][N][C]               : @25 MB,  4 MB
    //   v  bf16 [B][C][N]                : @29 MB,  4 MB
    //   wt bf16 [9][4][128][32]          : @33 MB,  294,912 B
    char* wsb = (char*)d_ws;
    u16*   att_t  = (u16*)wsb;
    float* ctx_up = (float*)(wsb + (5u << 20));
    float* acc    = (float*)(wsb + (5u << 20));           // overlays ctx_up
    float* lacc   = acc + (size_t)NB * NN * C;            // 2,097,152 f32 in
    u16*   q_t    = (u16*)(wsb + (21u << 20));
    u16*   k_t    = (u16*)(wsb + (25u << 20));
    u16*   v_bf   = (u16*)(wsb + (29u << 20));
    u16*   wt     = (u16*)(wsb + (33u << 20));

    upsample_kernel<<<dim3((NB * CCH * NN) / 256), 256, 0, stream>>>(ctx, ctx_up);
    zero_att<<<dim3(1089), 256, 0, stream>>>((uint4*)att_t);
    wprep<<<dim3(576), 256, 0, stream>>>(Wp, wt);
    proj_gemm_tn<<<dim3(NN / 64, C / 64, NB), 256, 0, stream>>>(sr, Wq, bq, q_t, C);
    proj_gemm_tn<<<dim3(NN / 64, C / 64, NB), 256, 0, stream>>>(ctx_up, Wk, bk, k_t, CCH);
    proj_gemm_nn<<<dim3(NN / 64, C / 64, NB), 256, 0, stream>>>(ctx_up, Wv, bv, v_bf, CCH);
    zero_acc<<<dim3(2064), 256, 0, stream>>>((uint4*)acc);   // after ctx_up is dead
    flash_mfma<<<dim3(1024), 256, 0, stream>>>(q_t, k_t, v_bf, acc, lacc);
    flash_combine<<<dim3(8192), 256, 0, stream>>>(acc, lacc, att_t);
    conv3x3_mfma<<<dim3(256), 256, 0, stream>>>(att_t, wt, bp, sr, gamma, out);
}